// Round 1
// baseline (2994.958 us; speedup 1.0000x reference)
//
#include <hip/hip_runtime.h>
#include <math.h>

#define Bb 16
#define Nn 2048
#define Dd 256
#define Cc 128
#define Kk 20
#define BIG_NEG -1.0e9f

// workspace layout (float offsets)
#define WS_EMIS   0
#define WS_MSC    (WS_EMIS + Bb*Nn*Cc)          // means * inv_var  [C][D]
#define WS_XQ     (WS_MSC + Cc*Dd)              // sum f^2*inv_var  [B*N]
#define WS_ECHAN  (WS_XQ + Bb*Nn)               // const - 0.5*mq   [C]
#define WS_T      (WS_ECHAN + Cc)               // exp(trans_lp)    [C][C]
#define WS_LEN    (WS_T + Cc*Cc)                // len_lp           [K][C]
#define WS_INIT   (WS_LEN + Kk*Cc)              // init_lp          [C]
#define WS_IVAR   (WS_INIT + Cc)                // 1/cov            [D]

// ---------------- small precompute (1 block, 256 threads) ----------------
__global__ void prep_kernel(const float* __restrict__ means,
                            const float* __restrict__ cov,
                            const float* __restrict__ tl,
                            const float* __restrict__ il,
                            const float* __restrict__ plr,
                            float* __restrict__ ws) {
  __shared__ float s_iv[Dd];
  __shared__ float s_red[4];
  __shared__ float s_tlse[Cc];
  int tid = threadIdx.x;

  // inv_var + log-det reduce
  float cv = cov[tid];
  float iv = 1.0f / cv;
  s_iv[tid] = iv;
  ws[WS_IVAR + tid] = iv;
  float lg = __logf(cv);
  #pragma unroll
  for (int off = 1; off < 64; off <<= 1) lg += __shfl_xor(lg, off, 64);
  if ((tid & 63) == 0) s_red[tid >> 6] = lg;
  __syncthreads();
  float logdet = s_red[0] + s_red[1] + s_red[2] + s_red[3];
  float cconst = -0.5f * ((float)Dd * 1.8378770664093453f + logdet);

  // msc = means * inv_var
  for (int idx = tid; idx < Cc * Dd; idx += 256) {
    int d = idx & (Dd - 1);
    ws[WS_MSC + idx] = means[idx] * s_iv[d];
  }
  // echan = const - 0.5 * sum_d means^2 * inv_var
  if (tid < Cc) {
    float acc = 0.0f;
    for (int d = 0; d < Dd; d++) {
      float m = means[tid * Dd + d];
      acc = fmaf(m * m, s_iv[d], acc);
    }
    ws[WS_ECHAN + tid] = cconst - 0.5f * acc;
  }
  // Poisson length table: len[L-1][c] = L*r - exp(r) - lgamma(L+1)
  for (int idx = tid; idx < Kk * Cc; idx += 256) {
    int L = idx / Cc + 1;
    int c = idx & (Cc - 1);
    float r = plr[c];
    ws[WS_LEN + idx] = (float)L * r - __expf(r) - lgammaf((float)(L + 1));
  }

  // init log-softmax over C
  __syncthreads();
  float x = (tid < Cc) ? il[tid] : -INFINITY;
  float mx = x;
  #pragma unroll
  for (int off = 1; off < 64; off <<= 1) mx = fmaxf(mx, __shfl_xor(mx, off, 64));
  if ((tid & 63) == 0) s_red[tid >> 6] = mx;
  __syncthreads();
  float M = fmaxf(s_red[0], s_red[1]);
  float se = (tid < Cc) ? __expf(x - M) : 0.0f;
  #pragma unroll
  for (int off = 1; off < 64; off <<= 1) se += __shfl_xor(se, off, 64);
  __syncthreads();
  if ((tid & 63) == 0) s_red[tid >> 6] = se;
  __syncthreads();
  float lse = M + __logf(s_red[0] + s_red[1]);
  if (tid < Cc) ws[WS_INIT + tid] = x - lse;

  // T = exp(log_softmax(masked, axis=0)); diag exactly 0
  if (tid < Cc) {
    int j = tid;
    float m2 = -INFINITY;
    for (int i = 0; i < Cc; i++) if (i != j) m2 = fmaxf(m2, tl[i * Cc + j]);
    float s2 = 0.0f;
    for (int i = 0; i < Cc; i++) if (i != j) s2 += __expf(tl[i * Cc + j] - m2);
    s_tlse[j] = m2 + __logf(s2);
  }
  __syncthreads();
  for (int idx = tid; idx < Cc * Cc; idx += 256) {
    int i = idx / Cc;
    int j = idx & (Cc - 1);
    ws[WS_T + idx] = (i == j) ? 0.0f : __expf(tl[idx] - s_tlse[j]);
  }
}

// ---------------- xq[b,n] = sum_d f^2 * inv_var (one wave per position) ----------------
__global__ void xq_kernel(const float* __restrict__ f, float* __restrict__ ws) {
  int pos = blockIdx.x * 4 + (threadIdx.x >> 6);
  int lane = threadIdx.x & 63;
  const float4 fv = *(const float4*)&f[(size_t)pos * Dd + lane * 4];
  const float4 vv = *(const float4*)&ws[WS_IVAR + lane * 4];
  float a = fv.x * fv.x * vv.x + fv.y * fv.y * vv.y +
            fv.z * fv.z * vv.z + fv.w * fv.w * vv.w;
  #pragma unroll
  for (int off = 1; off < 64; off <<= 1) a += __shfl_xor(a, off, 64);
  if (lane == 0) ws[WS_XQ + pos] = a;
}

// ---------------- emission matmul: emis[b,n,c] = echan[c] - 0.5*xq + f . msc[c] ----------------
__global__ void emis_kernel(const float* __restrict__ f, float* __restrict__ ws) {
  __shared__ float fA[32][32];    // [n][dd]
  __shared__ float msT[32][Cc];   // [dd][c]
  const float* msc = ws + WS_MSC;
  float* emis = ws + WS_EMIS;
  int tid = threadIdx.x;
  int b = blockIdx.x >> 6;            // N/32 = 64 tiles per batch
  int n0 = (blockIdx.x & 63) << 5;
  int c = tid & (Cc - 1), g = tid >> 7;
  float acc[16];
  #pragma unroll
  for (int i = 0; i < 16; i++) acc[i] = 0.0f;

  for (int d0 = 0; d0 < Dd; d0 += 32) {
    int row = tid >> 3, col = (tid & 7) << 2;
    *(float4*)&fA[row][col] =
        *(const float4*)&f[(size_t)(b * Nn + n0 + row) * Dd + d0 + col];
    int cc = tid & 127, dd0 = (tid >> 7) << 4;
    float4 v0 = *(const float4*)&msc[cc * Dd + d0 + dd0];
    float4 v1 = *(const float4*)&msc[cc * Dd + d0 + dd0 + 4];
    float4 v2 = *(const float4*)&msc[cc * Dd + d0 + dd0 + 8];
    float4 v3 = *(const float4*)&msc[cc * Dd + d0 + dd0 + 12];
    msT[dd0 + 0][cc] = v0.x; msT[dd0 + 1][cc] = v0.y;
    msT[dd0 + 2][cc] = v0.z; msT[dd0 + 3][cc] = v0.w;
    msT[dd0 + 4][cc] = v1.x; msT[dd0 + 5][cc] = v1.y;
    msT[dd0 + 6][cc] = v1.z; msT[dd0 + 7][cc] = v1.w;
    msT[dd0 + 8][cc] = v2.x; msT[dd0 + 9][cc] = v2.y;
    msT[dd0 + 10][cc] = v2.z; msT[dd0 + 11][cc] = v2.w;
    msT[dd0 + 12][cc] = v3.x; msT[dd0 + 13][cc] = v3.y;
    msT[dd0 + 14][cc] = v3.z; msT[dd0 + 15][cc] = v3.w;
    __syncthreads();
    #pragma unroll
    for (int dd = 0; dd < 32; dd++) {
      float mv = msT[dd][c];
      #pragma unroll
      for (int n = 0; n < 16; n++)
        acc[n] = fmaf(fA[g * 16 + n][dd], mv, acc[n]);
    }
    __syncthreads();
  }
  float ec = ws[WS_ECHAN + c];
  #pragma unroll
  for (int n = 0; n < 16; n++) {
    int nn = n0 + g * 16 + n;
    emis[(size_t)(b * Nn + nn) * Cc + c] = ec - 0.5f * ws[WS_XQ + b * Nn + nn] + acc[n];
  }
}

// ---------------- sequential semi-Markov scan: one block per batch ----------------
__launch_bounds__(256, 1)
__global__ void scan_kernel(const int* __restrict__ lengths,
                            const float* __restrict__ ws,
                            float* __restrict__ out) {
  __shared__ __align__(16) float lds_p[Cc];
  __shared__ float lds_qp[Cc];
  __shared__ float lds_wmax[2];
  __shared__ float lds_ps[2];
  int tid = threadIdx.x;
  int b = blockIdx.x;
  int c = tid & (Cc - 1);
  int h = tid >> 7;            // wave-uniform
  int lane = tid & 63;
  int len_b = lengths[b];
  const float* T = ws + WS_T;
  const float* emis = ws + WS_EMIS + (size_t)b * Nn * Cc;

  // per-thread T half-row (64 floats in VGPRs)
  float4 Trow[16];
  #pragma unroll
  for (int j = 0; j < 16; j++)
    Trow[j] = *(const float4*)&T[c * Cc + h * 64 + j * 4];

  float len_reg[Kk];
  #pragma unroll
  for (int i = 0; i < Kk; i++) len_reg[i] = ws[WS_LEN + i * Cc + c];

  float b_hist[Kk], e_hist[Kk];
  #pragma unroll
  for (int i = 0; i < Kk; i++) { b_hist[i] = BIG_NEG; e_hist[i] = 0.0f; }
  b_hist[0] = ws[WS_INIT + c];          // beta at time 0 = init_lp
  e_hist[0] = emis[0 * Cc + c];         // emis[t-1] for t=1
  float e_next  = emis[1 * Cc + c];
  float e_next2 = emis[2 * Cc + c];

  for (int t = 1; t <= Nn; t++) {
    int pf = t + 2; if (pf > Nn - 1) pf = Nn - 1;
    float e_load = emis[(size_t)pf * Cc + c];   // prefetch, consumed 2 steps later

    // ---- Phase A: alpha_t[c] = LSE_L (beta[t-L] + len[L] + sum emis[t-L..t-1])
    float m_c = -INFINITY, s_c = 0.0f, p_c = 0.0f;
    float v[Kk];
    if (h == 0) {
      float seg = 0.0f;
      #pragma unroll
      for (int i = 0; i < Kk; i++) {
        seg += e_hist[i];
        v[i] = b_hist[i] + len_reg[i] + seg;
        m_c = fmaxf(m_c, v[i]);
      }
      #pragma unroll
      for (int i = 0; i < Kk; i++) s_c += __expf(v[i] - m_c);
    }
    // block max of m_c (over 128 h==0 threads)
    float wm = m_c;
    #pragma unroll
    for (int off = 1; off < 64; off <<= 1) wm = fmaxf(wm, __shfl_xor(wm, off, 64));
    if (h == 0 && lane == 0) lds_wmax[tid >> 6] = wm;
    __syncthreads();                                   // barrier 1
    float Mt = fmaxf(lds_wmax[0], lds_wmax[1]);
    bool is_out = (t == len_b);
    if (h == 0) {
      p_c = s_c * __expf(m_c - Mt);                    // scaled prob, in [0, 20]
      lds_p[c] = p_c;
    }
    __syncthreads();                                   // barrier 2

    // ---- Phase B: q[c] = sum_{c'} T[c][c'] * p[c'] (each thread 64 terms)
    float acc = 0.0f;
    const float4* p4 = (const float4*)&lds_p[h * 64];
    #pragma unroll
    for (int j = 0; j < 16; j++) {
      float4 pv = p4[j];
      acc = fmaf(Trow[j].x, pv.x, acc);
      acc = fmaf(Trow[j].y, pv.y, acc);
      acc = fmaf(Trow[j].z, pv.z, acc);
      acc = fmaf(Trow[j].w, pv.w, acc);
    }
    if (h == 1) lds_qp[c] = acc;
    if (is_out && h == 0) {                            // logZ = Mt + log(sum p)
      float ps = p_c;
      #pragma unroll
      for (int off = 1; off < 64; off <<= 1) ps += __shfl_xor(ps, off, 64);
      if (lane == 0) lds_ps[tid >> 6] = ps;
    }
    __syncthreads();                                   // barrier 3

    // ---- Phase C: beta_t, shift history
    if (h == 0) {
      float q = acc + lds_qp[c];
      float beta = Mt + ((q > 0.0f) ? __logf(q) : -80.0f);
      #pragma unroll
      for (int i = Kk - 1; i > 0; i--) { b_hist[i] = b_hist[i - 1]; e_hist[i] = e_hist[i - 1]; }
      b_hist[0] = beta;
      e_hist[0] = e_next;
    }
    e_next = e_next2;
    e_next2 = e_load;
    if (is_out && tid == 0) out[b] = Mt + __logf(lds_ps[0] + lds_ps[1]);
  }
}

extern "C" void kernel_launch(void* const* d_in, const int* in_sizes, int n_in,
                              void* d_out, int out_size, void* d_ws, size_t ws_size,
                              hipStream_t stream) {
  const float* features = (const float*)d_in[0];
  const int* lengths = (const int*)d_in[1];
  const float* means = (const float*)d_in[2];
  const float* cov = (const float*)d_in[3];
  const float* tl = (const float*)d_in[4];
  const float* il = (const float*)d_in[5];
  const float* plr = (const float*)d_in[6];
  float* out = (float*)d_out;
  float* ws = (float*)d_ws;

  prep_kernel<<<1, 256, 0, stream>>>(means, cov, tl, il, plr, ws);
  xq_kernel<<<(Bb * Nn) / 4, 256, 0, stream>>>(features, ws);
  emis_kernel<<<Bb * (Nn / 32), 256, 0, stream>>>(features, ws);
  scan_kernel<<<Bb, 256, 0, stream>>>(lengths, ws, out);
}

// Round 2
// 2180.046 us; speedup vs baseline: 1.3738x; 1.3738x over previous
//
#include <hip/hip_runtime.h>
#include <math.h>

#define Bb 16
#define Nn 2048
#define Dd 256
#define Cc 128
#define Kk 20
#define BIG_NEG -1.0e9f

// workspace layout (float offsets)
#define WS_EMIS   0
#define WS_MSC    (WS_EMIS + Bb*Nn*Cc)          // means * inv_var  [C][D]
#define WS_XQ     (WS_MSC + Cc*Dd)              // sum f^2*inv_var  [B*N]
#define WS_ECHAN  (WS_XQ + Bb*Nn)               // const - 0.5*mq   [C]
#define WS_T      (WS_ECHAN + Cc)               // exp(trans_lp)    [C][C]
#define WS_LEN    (WS_T + Cc*Cc)                // len_lp           [K][C]
#define WS_INIT   (WS_LEN + Kk*Cc)              // init_lp          [C]
#define WS_IVAR   (WS_INIT + Cc)                // 1/cov            [D]

typedef __attribute__((ext_vector_type(8))) short short8;
typedef __attribute__((ext_vector_type(4))) float float4v;

__device__ __forceinline__ unsigned short f32_to_bf16(float x) {
  unsigned int u = __builtin_bit_cast(unsigned int, x);
  u = (u + 0x7FFFu + ((u >> 16) & 1u)) >> 16;
  return (unsigned short)u;
}

// ---------------- small precompute (1 block, 256 threads) ----------------
__global__ void prep_kernel(const float* __restrict__ means,
                            const float* __restrict__ cov,
                            const float* __restrict__ tl,
                            const float* __restrict__ il,
                            const float* __restrict__ plr,
                            float* __restrict__ ws) {
  __shared__ float s_iv[Dd];
  __shared__ float s_red[4];
  __shared__ float s_tlse[Cc];
  int tid = threadIdx.x;

  float cv = cov[tid];
  float iv = 1.0f / cv;
  s_iv[tid] = iv;
  ws[WS_IVAR + tid] = iv;
  float lg = __logf(cv);
  #pragma unroll
  for (int off = 1; off < 64; off <<= 1) lg += __shfl_xor(lg, off, 64);
  if ((tid & 63) == 0) s_red[tid >> 6] = lg;
  __syncthreads();
  float logdet = s_red[0] + s_red[1] + s_red[2] + s_red[3];
  float cconst = -0.5f * ((float)Dd * 1.8378770664093453f + logdet);

  for (int idx = tid; idx < Cc * Dd; idx += 256) {
    int d = idx & (Dd - 1);
    ws[WS_MSC + idx] = means[idx] * s_iv[d];
  }
  if (tid < Cc) {
    float acc = 0.0f;
    for (int d = 0; d < Dd; d++) {
      float m = means[tid * Dd + d];
      acc = fmaf(m * m, s_iv[d], acc);
    }
    ws[WS_ECHAN + tid] = cconst - 0.5f * acc;
  }
  for (int idx = tid; idx < Kk * Cc; idx += 256) {
    int L = idx / Cc + 1;
    int c = idx & (Cc - 1);
    float r = plr[c];
    ws[WS_LEN + idx] = (float)L * r - __expf(r) - lgammaf((float)(L + 1));
  }

  __syncthreads();
  float x = (tid < Cc) ? il[tid] : -INFINITY;
  float mx = x;
  #pragma unroll
  for (int off = 1; off < 64; off <<= 1) mx = fmaxf(mx, __shfl_xor(mx, off, 64));
  if ((tid & 63) == 0) s_red[tid >> 6] = mx;
  __syncthreads();
  float M = fmaxf(s_red[0], s_red[1]);
  float se = (tid < Cc) ? __expf(x - M) : 0.0f;
  #pragma unroll
  for (int off = 1; off < 64; off <<= 1) se += __shfl_xor(se, off, 64);
  __syncthreads();
  if ((tid & 63) == 0) s_red[tid >> 6] = se;
  __syncthreads();
  float lse = M + __logf(s_red[0] + s_red[1]);
  if (tid < Cc) ws[WS_INIT + tid] = x - lse;

  if (tid < Cc) {
    int j = tid;
    float m2 = -INFINITY;
    for (int i = 0; i < Cc; i++) if (i != j) m2 = fmaxf(m2, tl[i * Cc + j]);
    float s2 = 0.0f;
    for (int i = 0; i < Cc; i++) if (i != j) s2 += __expf(tl[i * Cc + j] - m2);
    s_tlse[j] = m2 + __logf(s2);
  }
  __syncthreads();
  for (int idx = tid; idx < Cc * Cc; idx += 256) {
    int i = idx / Cc;
    int j = idx & (Cc - 1);
    ws[WS_T + idx] = (i == j) ? 0.0f : __expf(tl[idx] - s_tlse[j]);
  }
}

// ---------------- xq[b,n] = sum_d f^2 * inv_var (one wave per position) ----------------
__global__ void xq_kernel(const float* __restrict__ f, float* __restrict__ ws) {
  int pos = blockIdx.x * 4 + (threadIdx.x >> 6);
  int lane = threadIdx.x & 63;
  const float4 fv = *(const float4*)&f[(size_t)pos * Dd + lane * 4];
  const float4 vv = *(const float4*)&ws[WS_IVAR + lane * 4];
  float a = fv.x * fv.x * vv.x + fv.y * fv.y * vv.y +
            fv.z * fv.z * vv.z + fv.w * fv.w * vv.w;
  #pragma unroll
  for (int off = 1; off < 64; off <<= 1) a += __shfl_xor(a, off, 64);
  if (lane == 0) ws[WS_XQ + pos] = a;
}

// ---------------- emission matmul: emis[b,n,c] = echan[c] - 0.5*xq + f . msc[c] ----------------
__global__ void emis_kernel(const float* __restrict__ f, float* __restrict__ ws) {
  __shared__ float fA[32][32];
  __shared__ float msT[32][Cc];
  const float* msc = ws + WS_MSC;
  float* emis = ws + WS_EMIS;
  int tid = threadIdx.x;
  int b = blockIdx.x >> 6;
  int n0 = (blockIdx.x & 63) << 5;
  int c = tid & (Cc - 1), g = tid >> 7;
  float acc[16];
  #pragma unroll
  for (int i = 0; i < 16; i++) acc[i] = 0.0f;

  for (int d0 = 0; d0 < Dd; d0 += 32) {
    int row = tid >> 3, col = (tid & 7) << 2;
    *(float4*)&fA[row][col] =
        *(const float4*)&f[(size_t)(b * Nn + n0 + row) * Dd + d0 + col];
    int cc = tid & 127, dd0 = (tid >> 7) << 4;
    float4 v0 = *(const float4*)&msc[cc * Dd + d0 + dd0];
    float4 v1 = *(const float4*)&msc[cc * Dd + d0 + dd0 + 4];
    float4 v2 = *(const float4*)&msc[cc * Dd + d0 + dd0 + 8];
    float4 v3 = *(const float4*)&msc[cc * Dd + d0 + dd0 + 12];
    msT[dd0 + 0][cc] = v0.x; msT[dd0 + 1][cc] = v0.y;
    msT[dd0 + 2][cc] = v0.z; msT[dd0 + 3][cc] = v0.w;
    msT[dd0 + 4][cc] = v1.x; msT[dd0 + 5][cc] = v1.y;
    msT[dd0 + 6][cc] = v1.z; msT[dd0 + 7][cc] = v1.w;
    msT[dd0 + 8][cc] = v2.x; msT[dd0 + 9][cc] = v2.y;
    msT[dd0 + 10][cc] = v2.z; msT[dd0 + 11][cc] = v2.w;
    msT[dd0 + 12][cc] = v3.x; msT[dd0 + 13][cc] = v3.y;
    msT[dd0 + 14][cc] = v3.z; msT[dd0 + 15][cc] = v3.w;
    __syncthreads();
    #pragma unroll
    for (int dd = 0; dd < 32; dd++) {
      float mv = msT[dd][c];
      #pragma unroll
      for (int n = 0; n < 16; n++)
        acc[n] = fmaf(fA[g * 16 + n][dd], mv, acc[n]);
    }
    __syncthreads();
  }
  float ec = ws[WS_ECHAN + c];
  #pragma unroll
  for (int n = 0; n < 16; n++) {
    int nn = n0 + g * 16 + n;
    emis[(size_t)(b * Nn + nn) * Cc + c] = ec - 0.5f * ws[WS_XQ + b * Nn + nn] + acc[n];
  }
}

// ---------------- sequential semi-Markov scan: one block (128 thr) per batch ----------------
__launch_bounds__(128, 1)
__global__ void scan_kernel(const int* __restrict__ lengths,
                            const float* __restrict__ ws,
                            float* __restrict__ out) {
  __shared__ __align__(16) unsigned short lds_pb[Cc];  // p, bf16
  __shared__ __align__(16) float lds_q[Cc];
  __shared__ float lds_wmax[2];
  __shared__ float lds_ps[2];
  int tid = threadIdx.x;
  int b = blockIdx.x;
  int c = tid;                 // channel 0..127
  int w = tid >> 6;            // wave 0..1
  int lane = tid & 63;
  int len_b = lengths[b];
  const float* emis = ws + WS_EMIS + (size_t)b * Nn * Cc;

  // ---- preload T fragments in bf16 (wave w covers q-rows [w*64, w*64+64)) ----
  // A-frag for tile (mt,kt): lane holds T[w*64+mt*16+(lane&15)][kt*32+(lane>>4)*8+j]
  short8 Tf[4][4];
  {
    const float* T = ws + WS_T;
    int row_lo = w * 64 + (lane & 15);
    int kg = (lane >> 4) * 8;
    #pragma unroll
    for (int mt = 0; mt < 4; mt++)
      #pragma unroll
      for (int kt = 0; kt < 4; kt++) {
        const float* src = &T[(size_t)(row_lo + mt * 16) * Cc + kt * 32 + kg];
        short8 fr;
        #pragma unroll
        for (int j = 0; j < 8; j++) fr[j] = (short)f32_to_bf16(src[j]);
        Tf[mt][kt] = fr;
      }
  }

  // ---- length table -> len0 + deltas (shift-with-add) ----
  float lenv[Kk];
  #pragma unroll
  for (int i = 0; i < Kk; i++) lenv[i] = ws[WS_LEN + i * Cc + c];
  float len0 = lenv[0];
  float dlen[Kk - 1];
  #pragma unroll
  for (int i = 1; i < Kk; i++) dlen[i - 1] = lenv[i] - lenv[i - 1];

  // h[i] = (beta[t-L] - cum[t-L]) + len[L], L = i+1
  float h[Kk];
  #pragma unroll
  for (int i = 0; i < Kk; i++) h[i] = BIG_NEG;
  h[0] = ws[WS_INIT + c] + len0;

  float cum = emis[0 * Cc + c];          // cum[1][c]
  float e0 = emis[1 * Cc + c];
  float e1 = emis[2 * Cc + c];
  float e2 = emis[3 * Cc + c];
  float e3 = emis[4 * Cc + c];

  for (int t = 1; t <= Nn; t++) {
    int pf = t + 4; if (pf > Nn - 1) pf = Nn - 1;
    float e_in = emis[(size_t)pf * Cc + c];

    // ---- Phase A: per-channel tree max over h, block max, scaled sum ----
    float m4[5], m2a, m2b, m2c;
    #pragma unroll
    for (int i = 0; i < 5; i++)
      m4[i] = fmaxf(fmaxf(h[4 * i], h[4 * i + 1]), fmaxf(h[4 * i + 2], h[4 * i + 3]));
    m2a = fmaxf(m4[0], m4[1]); m2b = fmaxf(m4[2], m4[3]); m2c = m4[4];
    float mloc = fmaxf(fmaxf(m2a, m2b), m2c);
    float mabs = mloc + cum;

    float bm = mabs;
    #pragma unroll
    for (int off = 1; off < 64; off <<= 1) bm = fmaxf(bm, __shfl_xor(bm, off, 64));
    if (lane == 0) lds_wmax[w] = bm;

    // s = sum exp(h - mloc)  (independent of block max -> overlaps butterfly)
    float ex[Kk];
    #pragma unroll
    for (int i = 0; i < Kk; i++) ex[i] = __expf(h[i] - mloc);
    float s4[5];
    #pragma unroll
    for (int i = 0; i < 5; i++)
      s4[i] = (ex[4 * i] + ex[4 * i + 1]) + (ex[4 * i + 2] + ex[4 * i + 3]);
    float s = ((s4[0] + s4[1]) + (s4[2] + s4[3])) + s4[4];

    __syncthreads();                               // barrier 1
    float Mt = fmaxf(lds_wmax[0], lds_wmax[1]);
    float rel = cum - Mt;
    float p = s * __expf(mabs - Mt);               // p in [0, 20]
    lds_pb[c] = f32_to_bf16(p);

    bool is_out = (t == len_b);
    if (is_out) {
      float ps = p;
      #pragma unroll
      for (int off = 1; off < 64; off <<= 1) ps += __shfl_xor(ps, off, 64);
      if (lane == 0) lds_ps[w] = ps;
    }
    __syncthreads();                               // barrier 2

    // ---- Phase B: q = T*p via MFMA (p replicated across all 16 B-cols) ----
    short8 bfrag[4];
    #pragma unroll
    for (int kt = 0; kt < 4; kt++)
      bfrag[kt] = *(const short8*)&lds_pb[kt * 32 + (lane >> 4) * 8];
    #pragma unroll
    for (int mt = 0; mt < 4; mt++) {
      float4v acc = {0.0f, 0.0f, 0.0f, 0.0f};
      #pragma unroll
      for (int kt = 0; kt < 4; kt++)
        acc = __builtin_amdgcn_mfma_f32_16x16x32_bf16(Tf[mt][kt], bfrag[kt], acc, 0, 0, 0);
      if ((lane & 15) == 0)                        // col 0 lanes hold rows (lane>>4)*4 + r
        *(float4v*)&lds_q[w * 64 + mt * 16 + (lane >> 4) * 4] = acc;
    }
    if (is_out && tid == 0) out[b] = Mt + __logf(lds_ps[0] + lds_ps[1]);
    __syncthreads();                               // barrier 3

    // ---- Phase C: beta (g-form), shift history, advance cum ----
    float q = lds_q[c];
    float gnew = (q > 0.0f) ? (__logf(q) - rel) : (-80.0f - rel);
    #pragma unroll
    for (int i = Kk - 1; i > 0; i--) h[i] = h[i - 1] + dlen[i - 1];
    h[0] = gnew + len0;
    cum += e0;
    e0 = e1; e1 = e2; e2 = e3; e3 = e_in;
  }
}

extern "C" void kernel_launch(void* const* d_in, const int* in_sizes, int n_in,
                              void* d_out, int out_size, void* d_ws, size_t ws_size,
                              hipStream_t stream) {
  const float* features = (const float*)d_in[0];
  const int* lengths = (const int*)d_in[1];
  const float* means = (const float*)d_in[2];
  const float* cov = (const float*)d_in[3];
  const float* tl = (const float*)d_in[4];
  const float* il = (const float*)d_in[5];
  const float* plr = (const float*)d_in[6];
  float* out = (float*)d_out;
  float* ws = (float*)d_ws;

  prep_kernel<<<1, 256, 0, stream>>>(means, cov, tl, il, plr, ws);
  xq_kernel<<<(Bb * Nn) / 4, 256, 0, stream>>>(features, ws);
  emis_kernel<<<Bb * (Nn / 32), 256, 0, stream>>>(features, ws);
  scan_kernel<<<Bb, 128, 0, stream>>>(lengths, ws, out);
}

// Round 3
// 1699.886 us; speedup vs baseline: 1.7619x; 1.2825x over previous
//
#include <hip/hip_runtime.h>
#include <math.h>

#define Bb 16
#define Nn 2048
#define Dd 256
#define Cc 128
#define Kk 20
#define BIG_NEG -1.0e9f

// workspace layout (float offsets)
#define WS_EMIS   0
#define WS_MSC    (WS_EMIS + Bb*Nn*Cc)          // means * inv_var  [C][D]
#define WS_XQ     (WS_MSC + Cc*Dd)              // sum f^2*inv_var  [B*N]
#define WS_ECHAN  (WS_XQ + Bb*Nn)               // const - 0.5*mq   [C]
#define WS_T      (WS_ECHAN + Cc)               // exp(trans_lp)    [C][C]
#define WS_LEN    (WS_T + Cc*Cc)                // len_lp           [K][C]
#define WS_INIT   (WS_LEN + Kk*Cc)              // init_lp          [C]
#define WS_IVAR   (WS_INIT + Cc)                // 1/cov            [D]

typedef __attribute__((ext_vector_type(8))) short short8;
typedef __attribute__((ext_vector_type(4))) float float4v;

__device__ __forceinline__ unsigned short f32_to_bf16(float x) {
  unsigned int u = __builtin_bit_cast(unsigned int, x);
  u = (u + 0x7FFFu + ((u >> 16) & 1u)) >> 16;
  return (unsigned short)u;
}

// DPP helpers: full 64-lane reduce in 6 VALU ops + readlane.
// update_dpp(old=x,...) leaves masked-out rows as x (no-op under fmax/add).
#define DPP_STEP(x, op, ctrl, rmask)                                          \
  do {                                                                        \
    int _yi = __builtin_amdgcn_update_dpp(                                    \
        __builtin_bit_cast(int, x), __builtin_bit_cast(int, x), ctrl, rmask,  \
        0xF, true);                                                           \
    x = op(x, __builtin_bit_cast(float, _yi));                                \
  } while (0)

__device__ __forceinline__ float dpp_add(float a, float b) { return a + b; }

__device__ __forceinline__ float wave_max64(float x) {
  DPP_STEP(x, fmaxf, 0xB1, 0xF);   // quad_perm [1,0,3,2]
  DPP_STEP(x, fmaxf, 0x4E, 0xF);   // quad_perm [2,3,0,1]
  DPP_STEP(x, fmaxf, 0x141, 0xF);  // row_half_mirror
  DPP_STEP(x, fmaxf, 0x140, 0xF);  // row_mirror: each 16-row has row max
  DPP_STEP(x, fmaxf, 0x142, 0xA);  // row_bcast:15 -> rows 1,3
  DPP_STEP(x, fmaxf, 0x143, 0xC);  // row_bcast:31 -> rows 2,3
  return __builtin_bit_cast(float,
      __builtin_amdgcn_readlane(__builtin_bit_cast(int, x), 63));
}

__device__ __forceinline__ float wave_sum64(float x) {
  DPP_STEP(x, dpp_add, 0xB1, 0xF);
  DPP_STEP(x, dpp_add, 0x4E, 0xF);
  DPP_STEP(x, dpp_add, 0x141, 0xF);
  DPP_STEP(x, dpp_add, 0x140, 0xF);
  DPP_STEP(x, dpp_add, 0x142, 0xA);
  DPP_STEP(x, dpp_add, 0x143, 0xC);
  return __builtin_bit_cast(float,
      __builtin_amdgcn_readlane(__builtin_bit_cast(int, x), 63));
}

// ---------------- small precompute (1 block, 256 threads) ----------------
__global__ void prep_kernel(const float* __restrict__ means,
                            const float* __restrict__ cov,
                            const float* __restrict__ tl,
                            const float* __restrict__ il,
                            const float* __restrict__ plr,
                            float* __restrict__ ws) {
  __shared__ float s_iv[Dd];
  __shared__ float s_red[4];
  __shared__ float s_tlse[Cc];
  int tid = threadIdx.x;

  float cv = cov[tid];
  float iv = 1.0f / cv;
  s_iv[tid] = iv;
  ws[WS_IVAR + tid] = iv;
  float lg = __logf(cv);
  #pragma unroll
  for (int off = 1; off < 64; off <<= 1) lg += __shfl_xor(lg, off, 64);
  if ((tid & 63) == 0) s_red[tid >> 6] = lg;
  __syncthreads();
  float logdet = s_red[0] + s_red[1] + s_red[2] + s_red[3];
  float cconst = -0.5f * ((float)Dd * 1.8378770664093453f + logdet);

  for (int idx = tid; idx < Cc * Dd; idx += 256) {
    int d = idx & (Dd - 1);
    ws[WS_MSC + idx] = means[idx] * s_iv[d];
  }
  if (tid < Cc) {
    float acc = 0.0f;
    for (int d = 0; d < Dd; d++) {
      float m = means[tid * Dd + d];
      acc = fmaf(m * m, s_iv[d], acc);
    }
    ws[WS_ECHAN + tid] = cconst - 0.5f * acc;
  }
  for (int idx = tid; idx < Kk * Cc; idx += 256) {
    int L = idx / Cc + 1;
    int c = idx & (Cc - 1);
    float r = plr[c];
    ws[WS_LEN + idx] = (float)L * r - __expf(r) - lgammaf((float)(L + 1));
  }

  __syncthreads();
  float x = (tid < Cc) ? il[tid] : -INFINITY;
  float mx = x;
  #pragma unroll
  for (int off = 1; off < 64; off <<= 1) mx = fmaxf(mx, __shfl_xor(mx, off, 64));
  if ((tid & 63) == 0) s_red[tid >> 6] = mx;
  __syncthreads();
  float M = fmaxf(s_red[0], s_red[1]);
  float se = (tid < Cc) ? __expf(x - M) : 0.0f;
  #pragma unroll
  for (int off = 1; off < 64; off <<= 1) se += __shfl_xor(se, off, 64);
  __syncthreads();
  if ((tid & 63) == 0) s_red[tid >> 6] = se;
  __syncthreads();
  float lse = M + __logf(s_red[0] + s_red[1]);
  if (tid < Cc) ws[WS_INIT + tid] = x - lse;

  if (tid < Cc) {
    int j = tid;
    float m2 = -INFINITY;
    for (int i = 0; i < Cc; i++) if (i != j) m2 = fmaxf(m2, tl[i * Cc + j]);
    float s2 = 0.0f;
    for (int i = 0; i < Cc; i++) if (i != j) s2 += __expf(tl[i * Cc + j] - m2);
    s_tlse[j] = m2 + __logf(s2);
  }
  __syncthreads();
  for (int idx = tid; idx < Cc * Cc; idx += 256) {
    int i = idx / Cc;
    int j = idx & (Cc - 1);
    ws[WS_T + idx] = (i == j) ? 0.0f : __expf(tl[idx] - s_tlse[j]);
  }
}

// ---------------- xq[b,n] = sum_d f^2 * inv_var (one wave per position) ----------------
__global__ void xq_kernel(const float* __restrict__ f, float* __restrict__ ws) {
  int pos = blockIdx.x * 4 + (threadIdx.x >> 6);
  int lane = threadIdx.x & 63;
  const float4 fv = *(const float4*)&f[(size_t)pos * Dd + lane * 4];
  const float4 vv = *(const float4*)&ws[WS_IVAR + lane * 4];
  float a = fv.x * fv.x * vv.x + fv.y * fv.y * vv.y +
            fv.z * fv.z * vv.z + fv.w * fv.w * vv.w;
  #pragma unroll
  for (int off = 1; off < 64; off <<= 1) a += __shfl_xor(a, off, 64);
  if (lane == 0) ws[WS_XQ + pos] = a;
}

// ---------------- emission matmul: emis[b,n,c] = echan[c] - 0.5*xq + f . msc[c] ----------------
__global__ void emis_kernel(const float* __restrict__ f, float* __restrict__ ws) {
  __shared__ float fA[32][32];
  __shared__ float msT[32][Cc];
  const float* msc = ws + WS_MSC;
  float* emis = ws + WS_EMIS;
  int tid = threadIdx.x;
  int b = blockIdx.x >> 6;
  int n0 = (blockIdx.x & 63) << 5;
  int c = tid & (Cc - 1), g = tid >> 7;
  float acc[16];
  #pragma unroll
  for (int i = 0; i < 16; i++) acc[i] = 0.0f;

  for (int d0 = 0; d0 < Dd; d0 += 32) {
    int row = tid >> 3, col = (tid & 7) << 2;
    *(float4*)&fA[row][col] =
        *(const float4*)&f[(size_t)(b * Nn + n0 + row) * Dd + d0 + col];
    int cc = tid & 127, dd0 = (tid >> 7) << 4;
    float4 v0 = *(const float4*)&msc[cc * Dd + d0 + dd0];
    float4 v1 = *(const float4*)&msc[cc * Dd + d0 + dd0 + 4];
    float4 v2 = *(const float4*)&msc[cc * Dd + d0 + dd0 + 8];
    float4 v3 = *(const float4*)&msc[cc * Dd + d0 + dd0 + 12];
    msT[dd0 + 0][cc] = v0.x; msT[dd0 + 1][cc] = v0.y;
    msT[dd0 + 2][cc] = v0.z; msT[dd0 + 3][cc] = v0.w;
    msT[dd0 + 4][cc] = v1.x; msT[dd0 + 5][cc] = v1.y;
    msT[dd0 + 6][cc] = v1.z; msT[dd0 + 7][cc] = v1.w;
    msT[dd0 + 8][cc] = v2.x; msT[dd0 + 9][cc] = v2.y;
    msT[dd0 + 10][cc] = v2.z; msT[dd0 + 11][cc] = v2.w;
    msT[dd0 + 12][cc] = v3.x; msT[dd0 + 13][cc] = v3.y;
    msT[dd0 + 14][cc] = v3.z; msT[dd0 + 15][cc] = v3.w;
    __syncthreads();
    #pragma unroll
    for (int dd = 0; dd < 32; dd++) {
      float mv = msT[dd][c];
      #pragma unroll
      for (int n = 0; n < 16; n++)
        acc[n] = fmaf(fA[g * 16 + n][dd], mv, acc[n]);
    }
    __syncthreads();
  }
  float ec = ws[WS_ECHAN + c];
  #pragma unroll
  for (int n = 0; n < 16; n++) {
    int nn = n0 + g * 16 + n;
    emis[(size_t)(b * Nn + nn) * Cc + c] = ec - 0.5f * ws[WS_XQ + b * Nn + nn] + acc[n];
  }
}

// ---------------- sequential semi-Markov scan: one block (128 thr) per batch ----------------
__launch_bounds__(128, 1)
__global__ void scan_kernel(const int* __restrict__ lengths,
                            const float* __restrict__ ws,
                            float* __restrict__ out) {
  __shared__ __align__(16) unsigned short lds_pb[2][Cc];  // p, bf16, ping-pong
  __shared__ float lds_wmax[2][2];                        // wave max, ping-pong
  __shared__ float lds_ps[2];
  int tid = threadIdx.x;
  int b = blockIdx.x;
  int c = tid;                 // channel 0..127
  int w = tid >> 6;            // wave 0..1
  int lane = tid & 63;
  int g = lane >> 4;           // 16-lane group 0..3
  int len_b = lengths[b];
  const float* emis = ws + WS_EMIS + (size_t)b * Nn * Cc;

  // ---- T fragments in bf16, used as the MFMA *B* operand this round ----
  // B-frag (kt,nt): lane holds B[k=kt*32+g*8+j][n=nt*16+(lane&15)]
  //               = T[w*64+nt*16+(lane&15)][kt*32+g*8+j]  (same bytes as round 2)
  short8 Tf[4][4];
  {
    const float* T = ws + WS_T;
    int row_lo = w * 64 + (lane & 15);
    int kg = g * 8;
    #pragma unroll
    for (int nt = 0; nt < 4; nt++)
      #pragma unroll
      for (int kt = 0; kt < 4; kt++) {
        const float* src = &T[(size_t)(row_lo + nt * 16) * Cc + kt * 32 + kg];
        short8 fr;
        #pragma unroll
        for (int j = 0; j < 8; j++) fr[j] = (short)f32_to_bf16(src[j]);
        Tf[nt][kt] = fr;
      }
  }

  // ---- length table -> len0 + deltas ----
  float lenv[Kk];
  #pragma unroll
  for (int i = 0; i < Kk; i++) lenv[i] = ws[WS_LEN + i * Cc + c];
  float len0 = lenv[0];
  float dlen[Kk - 1];
  #pragma unroll
  for (int i = 1; i < Kk; i++) dlen[i - 1] = lenv[i] - lenv[i - 1];

  // h[i] = (beta[t-L] - cum[t-L]) + len[L], L = i+1
  float h[Kk];
  #pragma unroll
  for (int i = 0; i < Kk; i++) h[i] = BIG_NEG;
  h[0] = ws[WS_INIT + c] + len0;

  float cum = emis[0 * Cc + c];          // cum[1][c]
  float e[8], en[8];
  #pragma unroll
  for (int i = 0; i < 8; i++) e[i] = emis[(size_t)(1 + i) * Cc + c];

  bool done = false;
  for (int tg = 1; tg <= Nn && !done; tg += 8) {
    // group prefetch: next 8 emission rows (vmcnt drain amortized over 8 steps)
    #pragma unroll
    for (int i = 0; i < 8; i++) {
      int r = tg + 8 + i; if (r > Nn - 1) r = Nn - 1;
      en[i] = emis[(size_t)r * Cc + c];
    }
    #pragma unroll
    for (int i = 0; i < 8; i++) {
      int t = tg + i;
      int buf = t & 1;

      // ---- Phase A: mloc = max h (h[0] last: shortest dep from prev step) ----
      float m2[10];
      #pragma unroll
      for (int k = 0; k < 9; k++) m2[k] = fmaxf(h[1 + 2 * k], h[2 + 2 * k]);
      m2[9] = h[19];
      float m4a = fmaxf(fmaxf(m2[0], m2[1]), fmaxf(m2[2], m2[3]));
      float m4b = fmaxf(fmaxf(m2[4], m2[5]), fmaxf(m2[6], m2[7]));
      float m19 = fmaxf(fmaxf(m4a, m4b), fmaxf(m2[8], m2[9]));
      float mloc = fmaxf(m19, h[0]);
      float mabs = mloc + cum;
      float wm = wave_max64(mabs);               // DPP, ~6 VALU ops

      float ex[Kk];
      #pragma unroll
      for (int k = 0; k < Kk; k++) ex[k] = __expf(h[k] - mloc);
      float s4[5];
      #pragma unroll
      for (int k = 0; k < 5; k++)
        s4[k] = (ex[4 * k] + ex[4 * k + 1]) + (ex[4 * k + 2] + ex[4 * k + 3]);
      float s = ((s4[0] + s4[1]) + (s4[2] + s4[3])) + s4[4];

      float p = s * __expf(mabs - wm);           // wave-local scale, p in [0,20]
      lds_pb[buf][c] = f32_to_bf16(p);
      if (lane == 0) lds_wmax[buf][w] = wm;
      bool is_out = (t == len_b);
      if (is_out) {
        float ps = wave_sum64(p);
        if (lane == 0) lds_ps[w] = ps;
      }
      __syncthreads();                           // the ONE barrier per step

      // ---- Phase B: q^T = p_repl x T^T; split-scale combine ----
      float MA = lds_wmax[buf][0], MB = lds_wmax[buf][1];
      float Mt = fmaxf(MA, MB);
      float sA = __expf(MA - Mt), sB = __expf(MB - Mt);

      const unsigned short* pb = lds_pb[buf];
      short8 pa[4];
      #pragma unroll
      for (int kt = 0; kt < 4; kt++)
        pa[kt] = *(const short8*)&pb[kt * 32 + g * 8];

      float4v accA[4], accB[4];
      #pragma unroll
      for (int nt = 0; nt < 4; nt++) {
        float4v z = {0.0f, 0.0f, 0.0f, 0.0f};
        accA[nt] = __builtin_amdgcn_mfma_f32_16x16x32_bf16(pa[1], Tf[nt][1],
                     __builtin_amdgcn_mfma_f32_16x16x32_bf16(pa[0], Tf[nt][0], z, 0, 0, 0),
                     0, 0, 0);
        accB[nt] = __builtin_amdgcn_mfma_f32_16x16x32_bf16(pa[3], Tf[nt][3],
                     __builtin_amdgcn_mfma_f32_16x16x32_bf16(pa[2], Tf[nt][2], z, 0, 0, 0),
                     0, 0, 0);
      }
      // all D rows identical -> q[c] = acc[nt=g][any reg], in-lane 4-way select
      float qa0 = (g == 0) ? accA[0][0] : accA[1][0];
      float qa1 = (g == 2) ? accA[2][0] : accA[3][0];
      float qa = (g < 2) ? qa0 : qa1;
      float qb0 = (g == 0) ? accB[0][0] : accB[1][0];
      float qb1 = (g == 2) ? accB[2][0] : accB[3][0];
      float qb = (g < 2) ? qb0 : qb1;
      float q = qa * sA + qb * sB;

      float rel = cum - Mt;
      float gnew = (q > 0.0f) ? (__logf(q) - rel) : (-80.0f - rel);

      if (is_out) {
        if (tid == 0) out[b] = Mt + __logf(lds_ps[0] * sA + lds_ps[1] * sB);
        done = true;
        break;
      }

      // ---- Phase C: shift history (g-form), advance cum ----
      #pragma unroll
      for (int k = Kk - 1; k > 0; k--) h[k] = h[k - 1] + dlen[k - 1];
      h[0] = gnew + len0;
      cum += e[i];
    }
    if (!done) {
      #pragma unroll
      for (int i = 0; i < 8; i++) e[i] = en[i];
    }
  }
}

extern "C" void kernel_launch(void* const* d_in, const int* in_sizes, int n_in,
                              void* d_out, int out_size, void* d_ws, size_t ws_size,
                              hipStream_t stream) {
  const float* features = (const float*)d_in[0];
  const int* lengths = (const int*)d_in[1];
  const float* means = (const float*)d_in[2];
  const float* cov = (const float*)d_in[3];
  const float* tl = (const float*)d_in[4];
  const float* il = (const float*)d_in[5];
  const float* plr = (const float*)d_in[6];
  float* out = (float*)d_out;
  float* ws = (float*)d_ws;

  prep_kernel<<<1, 256, 0, stream>>>(means, cov, tl, il, plr, ws);
  xq_kernel<<<(Bb * Nn) / 4, 256, 0, stream>>>(features, ws);
  emis_kernel<<<Bb * (Nn / 32), 256, 0, stream>>>(features, ws);
  scan_kernel<<<Bb, 128, 0, stream>>>(lengths, ws, out);
}

// Round 4
// 1540.708 us; speedup vs baseline: 1.9439x; 1.1033x over previous
//
#include <hip/hip_runtime.h>
#include <math.h>

#define Bb 16
#define Nn 2048
#define Dd 256
#define Cc 128
#define Kk 20
#define BIG_NEG -1.0e9f

// workspace layout (float offsets)
#define WS_EMIS   0
#define WS_MSC    (WS_EMIS + Bb*Nn*Cc)          // means * inv_var, bf16  [C][D]
#define WS_XQ     (WS_MSC + Cc*Dd)              // sum f^2*inv_var  [B*N]
#define WS_ECHAN  (WS_XQ + Bb*Nn)               // const - 0.5*mq   [C]
#define WS_T      (WS_ECHAN + Cc)               // exp(trans_lp)    [C][C]
#define WS_LEN    (WS_T + Cc*Cc)                // len_lp           [K][C]
#define WS_INIT   (WS_LEN + Kk*Cc)              // init_lp          [C]
#define WS_IVAR   (WS_INIT + Cc)                // 1/cov            [D]

typedef __attribute__((ext_vector_type(8))) short short8;
typedef __attribute__((ext_vector_type(4))) float float4v;

__device__ __forceinline__ unsigned short f32_to_bf16(float x) {
  unsigned int u = __builtin_bit_cast(unsigned int, x);
  u = (u + 0x7FFFu + ((u >> 16) & 1u)) >> 16;
  return (unsigned short)u;
}

#define DPP_STEP(x, op, ctrl, rmask)                                          \
  do {                                                                        \
    int _yi = __builtin_amdgcn_update_dpp(                                    \
        __builtin_bit_cast(int, x), __builtin_bit_cast(int, x), ctrl, rmask,  \
        0xF, true);                                                           \
    x = op(x, __builtin_bit_cast(float, _yi));                                \
  } while (0)

__device__ __forceinline__ float dpp_add(float a, float b) { return a + b; }

__device__ __forceinline__ float wave_max64(float x) {
  DPP_STEP(x, fmaxf, 0xB1, 0xF);
  DPP_STEP(x, fmaxf, 0x4E, 0xF);
  DPP_STEP(x, fmaxf, 0x141, 0xF);
  DPP_STEP(x, fmaxf, 0x140, 0xF);
  DPP_STEP(x, fmaxf, 0x142, 0xA);
  DPP_STEP(x, fmaxf, 0x143, 0xC);
  return __builtin_bit_cast(float,
      __builtin_amdgcn_readlane(__builtin_bit_cast(int, x), 63));
}

__device__ __forceinline__ float wave_sum64(float x) {
  DPP_STEP(x, dpp_add, 0xB1, 0xF);
  DPP_STEP(x, dpp_add, 0x4E, 0xF);
  DPP_STEP(x, dpp_add, 0x141, 0xF);
  DPP_STEP(x, dpp_add, 0x140, 0xF);
  DPP_STEP(x, dpp_add, 0x142, 0xA);
  DPP_STEP(x, dpp_add, 0x143, 0xC);
  return __builtin_bit_cast(float,
      __builtin_amdgcn_readlane(__builtin_bit_cast(int, x), 63));
}

// ---------------- small precompute (1 block, 256 threads) ----------------
__global__ void prep_kernel(const float* __restrict__ means,
                            const float* __restrict__ cov,
                            const float* __restrict__ tl,
                            const float* __restrict__ il,
                            const float* __restrict__ plr,
                            float* __restrict__ ws) {
  __shared__ float s_iv[Dd];
  __shared__ float s_red[4];
  __shared__ float s_tlse[Cc];
  int tid = threadIdx.x;

  float cv = cov[tid];
  float iv = 1.0f / cv;
  s_iv[tid] = iv;
  ws[WS_IVAR + tid] = iv;
  float lg = __logf(cv);
  #pragma unroll
  for (int off = 1; off < 64; off <<= 1) lg += __shfl_xor(lg, off, 64);
  if ((tid & 63) == 0) s_red[tid >> 6] = lg;
  __syncthreads();
  float logdet = s_red[0] + s_red[1] + s_red[2] + s_red[3];
  float cconst = -0.5f * ((float)Dd * 1.8378770664093453f + logdet);

  // msc in bf16 (B-frag operand for emission MFMA)
  unsigned short* mscb = (unsigned short*)(ws + WS_MSC);
  for (int idx = tid; idx < Cc * Dd; idx += 256) {
    int d = idx & (Dd - 1);
    mscb[idx] = f32_to_bf16(means[idx] * s_iv[d]);
  }
  if (tid < Cc) {
    float acc = 0.0f;
    for (int d = 0; d < Dd; d++) {
      float m = means[tid * Dd + d];
      acc = fmaf(m * m, s_iv[d], acc);
    }
    ws[WS_ECHAN + tid] = cconst - 0.5f * acc;
  }
  for (int idx = tid; idx < Kk * Cc; idx += 256) {
    int L = idx / Cc + 1;
    int c = idx & (Cc - 1);
    float r = plr[c];
    ws[WS_LEN + idx] = (float)L * r - __expf(r) - lgammaf((float)(L + 1));
  }

  __syncthreads();
  float x = (tid < Cc) ? il[tid] : -INFINITY;
  float mx = x;
  #pragma unroll
  for (int off = 1; off < 64; off <<= 1) mx = fmaxf(mx, __shfl_xor(mx, off, 64));
  if ((tid & 63) == 0) s_red[tid >> 6] = mx;
  __syncthreads();
  float M = fmaxf(s_red[0], s_red[1]);
  float se = (tid < Cc) ? __expf(x - M) : 0.0f;
  #pragma unroll
  for (int off = 1; off < 64; off <<= 1) se += __shfl_xor(se, off, 64);
  __syncthreads();
  if ((tid & 63) == 0) s_red[tid >> 6] = se;
  __syncthreads();
  float lse = M + __logf(s_red[0] + s_red[1]);
  if (tid < Cc) ws[WS_INIT + tid] = x - lse;

  if (tid < Cc) {
    int j = tid;
    float m2 = -INFINITY;
    for (int i = 0; i < Cc; i++) if (i != j) m2 = fmaxf(m2, tl[i * Cc + j]);
    float s2 = 0.0f;
    for (int i = 0; i < Cc; i++) if (i != j) s2 += __expf(tl[i * Cc + j] - m2);
    s_tlse[j] = m2 + __logf(s2);
  }
  __syncthreads();
  for (int idx = tid; idx < Cc * Cc; idx += 256) {
    int i = idx / Cc;
    int j = idx & (Cc - 1);
    ws[WS_T + idx] = (i == j) ? 0.0f : __expf(tl[idx] - s_tlse[j]);
  }
}

// ---------------- xq[b,n] = sum_d f^2 * inv_var (one wave per position) ----------------
__global__ void xq_kernel(const float* __restrict__ f, float* __restrict__ ws) {
  int pos = blockIdx.x * 4 + (threadIdx.x >> 6);
  int lane = threadIdx.x & 63;
  const float4 fv = *(const float4*)&f[(size_t)pos * Dd + lane * 4];
  const float4 vv = *(const float4*)&ws[WS_IVAR + lane * 4];
  float a = fv.x * fv.x * vv.x + fv.y * fv.y * vv.y +
            fv.z * fv.z * vv.z + fv.w * fv.w * vv.w;
  #pragma unroll
  for (int off = 1; off < 64; off <<= 1) a += __shfl_xor(a, off, 64);
  if (lane == 0) ws[WS_XQ + pos] = a;
}

// ---------------- emission via MFMA: 32n x 128c per block, 4 waves ----------------
__launch_bounds__(256)
__global__ void emis_mfma_kernel(const float* __restrict__ f, float* __restrict__ ws) {
  const unsigned short* msc = (const unsigned short*)(ws + WS_MSC);
  float* emis = ws + WS_EMIS;
  int tid = threadIdx.x;
  int w = tid >> 6, lane = tid & 63, g = lane >> 4, l16 = lane & 15;
  int b = blockIdx.x >> 6;
  int n0 = (blockIdx.x & 63) << 5;
  int c0 = w << 5;

  const float* fbase = f + (size_t)(b * Nn + n0) * Dd;
  float4v acc[2][2];
  #pragma unroll
  for (int rt = 0; rt < 2; rt++)
    #pragma unroll
    for (int ct = 0; ct < 2; ct++) acc[rt][ct] = (float4v){0.f, 0.f, 0.f, 0.f};

  #pragma unroll
  for (int k0 = 0; k0 < Dd; k0 += 32) {
    int kk = k0 + g * 8;
    short8 afr[2], bfr[2];
    #pragma unroll
    for (int rt = 0; rt < 2; rt++) {
      const float* src = fbase + (size_t)(rt * 16 + l16) * Dd + kk;
      float4 v0 = *(const float4*)src;
      float4 v1 = *(const float4*)(src + 4);
      short8 fr;
      fr[0] = (short)f32_to_bf16(v0.x); fr[1] = (short)f32_to_bf16(v0.y);
      fr[2] = (short)f32_to_bf16(v0.z); fr[3] = (short)f32_to_bf16(v0.w);
      fr[4] = (short)f32_to_bf16(v1.x); fr[5] = (short)f32_to_bf16(v1.y);
      fr[6] = (short)f32_to_bf16(v1.z); fr[7] = (short)f32_to_bf16(v1.w);
      afr[rt] = fr;
    }
    #pragma unroll
    for (int ct = 0; ct < 2; ct++)
      bfr[ct] = *(const short8*)&msc[(size_t)(c0 + ct * 16 + l16) * Dd + kk];
    #pragma unroll
    for (int rt = 0; rt < 2; rt++)
      #pragma unroll
      for (int ct = 0; ct < 2; ct++)
        acc[rt][ct] = __builtin_amdgcn_mfma_f32_16x16x32_bf16(afr[rt], bfr[ct], acc[rt][ct], 0, 0, 0);
  }

  #pragma unroll
  for (int rt = 0; rt < 2; rt++) {
    #pragma unroll
    for (int ct = 0; ct < 2; ct++) {
      int cc = c0 + ct * 16 + l16;
      float ec = ws[WS_ECHAN + cc];
      #pragma unroll
      for (int r = 0; r < 4; r++) {
        int row = rt * 16 + g * 4 + r;
        int nn = n0 + row;
        emis[(size_t)(b * Nn + nn) * Cc + cc] =
            ec - 0.5f * ws[WS_XQ + b * Nn + nn] + acc[rt][ct][r];
      }
    }
  }
}

// ---------------- sequential semi-Markov scan: one block (128 thr) per batch ----------------
__launch_bounds__(128, 1)
__global__ void scan_kernel(const int* __restrict__ lengths,
                            const float* __restrict__ ws,
                            float* __restrict__ out) {
  __shared__ __align__(16) unsigned short lds_pb[2][Cc];  // p, bf16, ping-pong
  __shared__ float lds_wmax[2][2];
  __shared__ float lds_ps[2];
  int tid = threadIdx.x;
  int b = blockIdx.x;
  int c = tid;
  int w = tid >> 6;
  int lane = tid & 63;
  int g = lane >> 4;
  int len_b = lengths[b];
  const float* emis = ws + WS_EMIS + (size_t)b * Nn * Cc;

  // T fragments (MFMA B operand): lane holds T[w*64+nt*16+(lane&15)][kt*32+g*8+j]
  short8 Tf[4][4];
  {
    const float* T = ws + WS_T;
    int row_lo = w * 64 + (lane & 15);
    int kg = g * 8;
    #pragma unroll
    for (int nt = 0; nt < 4; nt++)
      #pragma unroll
      for (int kt = 0; kt < 4; kt++) {
        const float* src = &T[(size_t)(row_lo + nt * 16) * Cc + kt * 32 + kg];
        short8 fr;
        #pragma unroll
        for (int j = 0; j < 8; j++) fr[j] = (short)f32_to_bf16(src[j]);
        Tf[nt][kt] = fr;
      }
  }

  float lenv[Kk];
  #pragma unroll
  for (int i = 0; i < Kk; i++) lenv[i] = ws[WS_LEN + i * Cc + c];
  float len0 = lenv[0];
  float dlen[Kk - 1];
  #pragma unroll
  for (int i = 1; i < Kk; i++) dlen[i - 1] = lenv[i] - lenv[i - 1];

  // h[i] = (beta[t-1-i] - cum[t-1-i]) + len[i+1]
  float h[Kk];
  #pragma unroll
  for (int i = 0; i < Kk; i++) h[i] = BIG_NEG;

  float gnew = ws[WS_INIT + c];     // h[0] at t=1 will be gnew + len0
  float pm = BIG_NEG;               // max over h[1..19] (all BIG_NEG)
  float ps = 19.0f;                 // sum exp(h[k]-pm) = 19; dies via exp(pm-m)=0

  float cum = emis[0 * Cc + c];
  float e[8], en[8];
  #pragma unroll
  for (int i = 0; i < 8; i++) e[i] = emis[(size_t)(1 + i) * Cc + c];

  bool done = false;
  for (int tg = 1; tg <= Nn && !done; tg += 8) {
    #pragma unroll
    for (int i = 0; i < 8; i++) {
      int t = tg + i;
      int buf = t & 1;

      // ---- pre-barrier: short fixup chain only ----
      float h0 = gnew + len0;
      float m = fmaxf(pm, h0);
      float sfix = fmaf(ps, __expf(pm - m), __expf(h0 - m));
      float mabs = m + cum;
      float wm = wave_max64(mabs);
      float p = sfix * __expf(mabs - wm);
      lds_pb[buf][c] = f32_to_bf16(p);
      if (lane == 0) lds_wmax[buf][w] = wm;
      bool is_out = (t == len_b);
      if (is_out) {
        float pssum = wave_sum64(p);
        if (lane == 0) lds_ps[w] = pssum;
      }
      h[0] = h0;
      __syncthreads();                        // the ONE barrier per step

      // ---- post-barrier ----
      if (i == 0) {                            // group prefetch: no drain at barriers
        #pragma unroll
        for (int j = 0; j < 8; j++) {
          int r = tg + 8 + j; if (r > Nn - 1) r = Nn - 1;
          en[j] = emis[(size_t)r * Cc + c];
        }
      }
      // issue LDS reads early
      float MA = lds_wmax[buf][0], MB = lds_wmax[buf][1];
      const unsigned short* pb = lds_pb[buf];
      short8 pa[4];
      #pragma unroll
      for (int kt = 0; kt < 4; kt++)
        pa[kt] = *(const short8*)&pb[kt * 32 + g * 8];

      // next-step precompute (fills LDS/MFMA latency window):
      // shift h, then pm/ps over h[1..19]
      #pragma unroll
      for (int k = Kk - 1; k > 0; k--) h[k] = h[k - 1] + dlen[k - 1];
      float m2[10];
      #pragma unroll
      for (int k = 0; k < 9; k++) m2[k] = fmaxf(h[1 + 2 * k], h[2 + 2 * k]);
      m2[9] = h[19];
      float m4a = fmaxf(fmaxf(m2[0], m2[1]), fmaxf(m2[2], m2[3]));
      float m4b = fmaxf(fmaxf(m2[4], m2[5]), fmaxf(m2[6], m2[7]));
      float pm2 = fmaxf(fmaxf(m4a, m4b), fmaxf(m2[8], m2[9]));
      float ex[Kk - 1];
      #pragma unroll
      for (int k = 1; k < Kk; k++) ex[k - 1] = __expf(h[k] - pm2);
      float s4[5];
      s4[0] = (ex[0] + ex[1]) + (ex[2] + ex[3]);
      s4[1] = (ex[4] + ex[5]) + (ex[6] + ex[7]);
      s4[2] = (ex[8] + ex[9]) + (ex[10] + ex[11]);
      s4[3] = (ex[12] + ex[13]) + (ex[14] + ex[15]);
      s4[4] = (ex[16] + ex[17]) + ex[18];
      float ps2 = ((s4[0] + s4[1]) + (s4[2] + s4[3])) + s4[4];

      // MFMA matvec: q^T = p_repl x T^T (split k-halves for wave scales)
      float4v z = {0.0f, 0.0f, 0.0f, 0.0f};
      float4v accA[4], accB[4];
      #pragma unroll
      for (int nt = 0; nt < 4; nt++) {
        accA[nt] = __builtin_amdgcn_mfma_f32_16x16x32_bf16(pa[1], Tf[nt][1],
                     __builtin_amdgcn_mfma_f32_16x16x32_bf16(pa[0], Tf[nt][0], z, 0, 0, 0),
                     0, 0, 0);
        accB[nt] = __builtin_amdgcn_mfma_f32_16x16x32_bf16(pa[3], Tf[nt][3],
                     __builtin_amdgcn_mfma_f32_16x16x32_bf16(pa[2], Tf[nt][2], z, 0, 0, 0),
                     0, 0, 0);
      }
      float Mt = fmaxf(MA, MB);
      float sA = __expf(MA - Mt), sB = __expf(MB - Mt);
      float qa0 = (g == 0) ? accA[0][0] : accA[1][0];
      float qa1 = (g == 2) ? accA[2][0] : accA[3][0];
      float qa = (g < 2) ? qa0 : qa1;
      float qb0 = (g == 0) ? accB[0][0] : accB[1][0];
      float qb1 = (g == 2) ? accB[2][0] : accB[3][0];
      float qb = (g < 2) ? qb0 : qb1;
      float q = qa * sA + qb * sB;

      float rel = cum - Mt;
      gnew = (q > 0.0f) ? (__logf(q) - rel) : (-80.0f - rel);

      if (is_out) {
        if (tid == 0) out[b] = Mt + __logf(lds_ps[0] * sA + lds_ps[1] * sB);
        done = true;
        break;
      }
      pm = pm2;
      ps = ps2;
      cum += e[i];
    }
    if (!done) {
      #pragma unroll
      for (int i = 0; i < 8; i++) e[i] = en[i];
    }
  }
}

extern "C" void kernel_launch(void* const* d_in, const int* in_sizes, int n_in,
                              void* d_out, int out_size, void* d_ws, size_t ws_size,
                              hipStream_t stream) {
  const float* features = (const float*)d_in[0];
  const int* lengths = (const int*)d_in[1];
  const float* means = (const float*)d_in[2];
  const float* cov = (const float*)d_in[3];
  const float* tl = (const float*)d_in[4];
  const float* il = (const float*)d_in[5];
  const float* plr = (const float*)d_in[6];
  float* out = (float*)d_out;
  float* ws = (float*)d_ws;

  prep_kernel<<<1, 256, 0, stream>>>(means, cov, tl, il, plr, ws);
  xq_kernel<<<(Bb * Nn) / 4, 256, 0, stream>>>(features, ws);
  emis_mfma_kernel<<<Bb * (Nn / 32), 256, 0, stream>>>(features, ws);
  scan_kernel<<<Bb, 128, 0, stream>>>(lengths, ws, out);
}